// Round 1
// baseline (438.763 us; speedup 1.0000x reference)
//
#include <hip/hip_runtime.h>
#include <math.h>

// Problem constants
#define BB   4
#define LQ   2048
#define LK   2048
#define HD   8
#define VD   64
#define HV   512     // HD*VD
#define OUTD 512

// Kernel-1 tiling
#define TQ 16
#define TK 64
#define KS 20             // k-stride (floats) in score LDS: 16 q + 4 pad
#define HS (TK*KS + 4)    // head stride: 1284 floats -> +4 banks per head

__global__ __launch_bounds__(256) void attend_kernel(
    const float* __restrict__ qpos,
    const float* __restrict__ kpos,
    const float* __restrict__ vals,
    const int*   __restrict__ kmask,
    const float* __restrict__ ls,
    float* __restrict__ attended)
{
    __shared__ float s_sc[HD * HS];       // scores [h][k][q]
    __shared__ float s_kp[TK * 3];
    __shared__ int   s_km[TK];
    __shared__ float s_qp[TQ * 3];
    __shared__ float s_pd[16 * HD * 16];  // partial-den reduce buffer [kgrp][h][q]
    __shared__ float s_inv[HD * 16];      // 1/(den+1e-5) [h][q]

    const int tid = threadIdx.x;
    const int bb  = blockIdx.y;
    const int q0  = blockIdx.x * TQ;

    float inv2[8];
#pragma unroll
    for (int h = 0; h < 8; ++h) { float l = ls[h]; inv2[h] = 1.0f / (l * l); }

    if (tid < TQ * 3) s_qp[tid] = qpos[(size_t)(bb * LQ + q0) * 3 + tid];

    // score-phase identity: q = tid&15, k-group = tid>>4
    const int sq  = tid & 15;
    const int skg = tid >> 4;
    // accum-phase identity: 8 heads x 4 q-quads x 8 v-octets
    const int vo = tid & 7;
    const int qg = (tid >> 3) & 3;
    const int hh = tid >> 5;

    float pden[8] = {0.f,0.f,0.f,0.f,0.f,0.f,0.f,0.f};
    float acc[4][8];
#pragma unroll
    for (int i = 0; i < 4; ++i)
#pragma unroll
        for (int j = 0; j < 8; ++j) acc[i][j] = 0.f;

    for (int kt = 0; kt < LK; kt += TK) {
        // ---- stage key positions + mask ----
        if (tid < TK * 3) s_kp[tid] = kpos[(size_t)(bb * LK + kt) * 3 + tid];
        if (tid < TK)     s_km[tid] = kmask[bb * LK + kt + tid];
        __syncthreads();   // also guards s_sc reuse vs previous accumulation

        // ---- scores ----
        {
            const float qpx = s_qp[sq * 3 + 0];
            const float qpy = s_qp[sq * 3 + 1];
            const float qpz = s_qp[sq * 3 + 2];
#pragma unroll
            for (int i = 0; i < 4; ++i) {
                const int k = skg + 16 * i;
                const float dx = qpx - s_kp[k * 3 + 0];
                const float dy = qpy - s_kp[k * 3 + 1];
                const float dz = qpz - s_kp[k * 3 + 2];
                const float d2 = dx * dx + dy * dy + dz * dz;
                const bool  m  = (s_km[k] != 0);
                float* sp = &s_sc[k * KS + sq];
#pragma unroll
                for (int h = 0; h < 8; ++h) {
                    const float sc = m ? 0.0f : __expf(-d2 * inv2[h]);
                    sp[h * HS] = sc;
                    pden[h] += sc;
                }
            }
        }
        __syncthreads();

        // ---- accumulate: per k, 8 v (2 float4) x 4 q ----
        const float* __restrict__ vb = vals + ((size_t)(bb * LK + kt) * HV + hh * VD + vo * 8);
        const float* __restrict__ sb = &s_sc[hh * HS + qg * 4];
#pragma unroll 4
        for (int kk = 0; kk < TK; ++kk) {
            const float4 v0 = *(const float4*)(vb + (size_t)kk * HV);
            const float4 v1 = *(const float4*)(vb + (size_t)kk * HV + 4);
            const float4 s4 = *(const float4*)(sb + kk * KS);
            const float sarr[4] = {s4.x, s4.y, s4.z, s4.w};
#pragma unroll
            for (int qi = 0; qi < 4; ++qi) {
                const float s = sarr[qi];
                acc[qi][0] += s * v0.x; acc[qi][1] += s * v0.y;
                acc[qi][2] += s * v0.z; acc[qi][3] += s * v0.w;
                acc[qi][4] += s * v1.x; acc[qi][5] += s * v1.y;
                acc[qi][6] += s * v1.z; acc[qi][7] += s * v1.w;
            }
        }
    }

    // ---- denominator reduction ----
#pragma unroll
    for (int h = 0; h < 8; ++h) s_pd[(skg * 8 + h) * 16 + sq] = pden[h];
    __syncthreads();
    if (tid < 128) {
        const int h = tid >> 4, q = tid & 15;
        float d = 1e-5f;
#pragma unroll
        for (int g = 0; g < 16; ++g) d += s_pd[(g * 8 + h) * 16 + q];
        s_inv[h * 16 + q] = 1.0f / d;
    }
    __syncthreads();

    // ---- epilogue: normalize + store attended [B*Lq][H*V] ----
#pragma unroll
    for (int qi = 0; qi < 4; ++qi) {
        const int q = qg * 4 + qi;
        const float inv = s_inv[hh * 16 + q];
        float* ob = attended + ((size_t)(bb * LQ + q0 + q) * HV + hh * VD + vo * 8);
        float4 o0 = make_float4(acc[qi][0] * inv, acc[qi][1] * inv,
                                acc[qi][2] * inv, acc[qi][3] * inv);
        float4 o1 = make_float4(acc[qi][4] * inv, acc[qi][5] * inv,
                                acc[qi][6] * inv, acc[qi][7] * inv);
        *(float4*)ob       = o0;
        *(float4*)(ob + 4) = o1;
    }
}

// C[M=8192][N=512] = A[M][K=512] * W[N][K]^T
__global__ __launch_bounds__(256) void proj_gemm(
    const float* __restrict__ A, const float* __restrict__ W, float* __restrict__ C)
{
    constexpr int NN = 512, KK = 512;
    constexpr int BM = 64, BN = 64, BKt = 16;
    __shared__ float As[BKt][BM + 4];
    __shared__ float Ws[BKt][BN + 4];

    const int tid = threadIdx.x;
    const int m0 = blockIdx.y * BM, n0 = blockIdx.x * BN;
    const int tm = tid >> 4, tn = tid & 15;
    const int lrow = tid >> 2, lk4 = (tid & 3) << 2;

    float acc[4][4];
#pragma unroll
    for (int i = 0; i < 4; ++i)
#pragma unroll
        for (int j = 0; j < 4; ++j) acc[i][j] = 0.f;

    for (int k0 = 0; k0 < KK; k0 += BKt) {
        const float4 va = *(const float4*)(A + (size_t)(m0 + lrow) * KK + k0 + lk4);
        const float4 vw = *(const float4*)(W + (size_t)(n0 + lrow) * KK + k0 + lk4);
        As[lk4 + 0][lrow] = va.x; As[lk4 + 1][lrow] = va.y;
        As[lk4 + 2][lrow] = va.z; As[lk4 + 3][lrow] = va.w;
        Ws[lk4 + 0][lrow] = vw.x; Ws[lk4 + 1][lrow] = vw.y;
        Ws[lk4 + 2][lrow] = vw.z; Ws[lk4 + 3][lrow] = vw.w;
        __syncthreads();
#pragma unroll
        for (int kk = 0; kk < BKt; ++kk) {
            const float4 a = *(const float4*)&As[kk][tm << 2];
            const float4 b = *(const float4*)&Ws[kk][tn << 2];
            acc[0][0] += a.x * b.x; acc[0][1] += a.x * b.y;
            acc[0][2] += a.x * b.z; acc[0][3] += a.x * b.w;
            acc[1][0] += a.y * b.x; acc[1][1] += a.y * b.y;
            acc[1][2] += a.y * b.z; acc[1][3] += a.y * b.w;
            acc[2][0] += a.z * b.x; acc[2][1] += a.z * b.y;
            acc[2][2] += a.z * b.z; acc[2][3] += a.z * b.w;
            acc[3][0] += a.w * b.x; acc[3][1] += a.w * b.y;
            acc[3][2] += a.w * b.z; acc[3][3] += a.w * b.w;
        }
        __syncthreads();
    }
#pragma unroll
    for (int i = 0; i < 4; ++i) {
        float4 o = make_float4(acc[i][0], acc[i][1], acc[i][2], acc[i][3]);
        *(float4*)(C + (size_t)(m0 + (tm << 2) + i) * NN + n0 + (tn << 2)) = o;
    }
}

extern "C" void kernel_launch(void* const* d_in, const int* in_sizes, int n_in,
                              void* d_out, int out_size, void* d_ws, size_t ws_size,
                              hipStream_t stream) {
    const float* qpos  = (const float*)d_in[0];   // [4,2048,3]
    const float* kpos  = (const float*)d_in[1];   // [4,2048,3]
    const float* vals  = (const float*)d_in[2];   // [4,2048,8,64]
    const int*   kmask = (const int*)  d_in[3];   // [4,2048]
    const float* ls    = (const float*)d_in[4];   // [8]
    const float* wout  = (const float*)d_in[5];   // [512,512]
    float* out = (float*)d_out;                   // [4,2048,512]
    float* att = (float*)d_ws;                    // [8192,512] scratch (16.8 MB)

    attend_kernel<<<dim3(LQ / TQ, BB), 256, 0, stream>>>(qpos, kpos, vals, kmask, ls, att);
    proj_gemm<<<dim3(OUTD / 64, (BB * LQ) / 64), 256, 0, stream>>>(att, wout, out);
}

// Round 2
// 168.193 us; speedup vs baseline: 2.6087x; 2.6087x over previous
//
#include <hip/hip_runtime.h>
#include <math.h>

#define BB   4
#define LQ   2048
#define LK   2048
#define HD   8
#define VD   64
#define HV   512
#define OUTD 512
#define SP   72          // padded LDS row stride in bf16 elems (144 B, 16B-aligned)

typedef __attribute__((ext_vector_type(8))) short  bf16x8;
typedef __attribute__((ext_vector_type(4))) float  f32x4;

static __device__ __forceinline__ unsigned short f2bf(float f) {
    unsigned u = __builtin_bit_cast(unsigned, f);
    unsigned r = (u + 0x7fffu + ((u >> 16) & 1u)) >> 16;
    return (unsigned short)r;
}

// ---------------- values fp32 [b][k][h][v] -> bf16 [b][h][v][k] ----------------
__global__ __launch_bounds__(256) void cvt_vals(
    const float* __restrict__ vals, unsigned short* __restrict__ vals_t)
{
    __shared__ unsigned short st[64 * SP];   // [v][k] tile
    const int tid = threadIdx.x;
    const int kt = blockIdx.x, h = blockIdx.y, b = blockIdx.z;

    const int k  = tid >> 2;
    const int vb = (tid & 3) * 16;
    const float* src = vals + (((size_t)(b * LK + kt * 64 + k) * HD + h)) * VD + vb;
    float4 f0 = *(const float4*)(src);
    float4 f1 = *(const float4*)(src + 4);
    float4 f2 = *(const float4*)(src + 8);
    float4 f3 = *(const float4*)(src + 12);
    const float fv[16] = {f0.x,f0.y,f0.z,f0.w, f1.x,f1.y,f1.z,f1.w,
                          f2.x,f2.y,f2.z,f2.w, f3.x,f3.y,f3.z,f3.w};
#pragma unroll
    for (int j = 0; j < 16; ++j) st[(vb + j) * SP + k] = f2bf(fv[j]);
    __syncthreads();

    const int v  = tid >> 2;
    const int kb = (tid & 3) * 16;
    uint4 o0 = *(const uint4*)&st[v * SP + kb];
    uint4 o1 = *(const uint4*)&st[v * SP + kb + 8];
    unsigned short* dst = vals_t + ((size_t)((b * HD + h) * VD + v)) * LK + kt * 64 + kb;
    *(uint4*)dst       = o0;
    *(uint4*)(dst + 8) = o1;
}

// ---------------- fused gaussian-score attention, bf16 MFMA ----------------
__global__ __launch_bounds__(256) void attend2(
    const float* __restrict__ qpos,
    const float* __restrict__ kpos,
    const unsigned short* __restrict__ vals_t,
    const int*   __restrict__ kmask,
    const float* __restrict__ ls,
    unsigned short* __restrict__ attended)
{
    __shared__ unsigned short sS[64 * SP];   // scores [q][k] bf16
    __shared__ unsigned short sV[64 * SP];   // V^T    [v][k] bf16
    __shared__ float s_kx[64], s_ky[64], s_kz[64];
    __shared__ float s_pd[256];
    __shared__ float s_inv[64];

    const int tid = threadIdx.x;
    const int qt = blockIdx.x, h = blockIdx.y, b = blockIdx.z;
    const int q0 = qt * 64;

    const float lsh  = ls[h];
    const float negc = -1.0f / (lsh * lsh);

    // score-phase identity
    const int sq = tid >> 2;      // q row 0..63
    const int so = tid & 3;       // octet base (this thread does octets so, so+4)
    const float* qp = qpos + (size_t)(b * LQ + q0 + sq) * 3;
    const float qx = qp[0], qy = qp[1], qz = qp[2];

    // V staging identity
    const int vv = tid >> 3;      // 0..31 (rows vv, vv+32)
    const int vc = tid & 7;       // 16B chunk
    const unsigned short* vt_base = vals_t + (size_t)((b * HD + h) * VD) * LK;

    // mfma identity
    const int wave = tid >> 6;
    const int lane = tid & 63;
    const int ln = lane & 15, kq = lane >> 4;

    float pden = 0.f;
    f32x4 acc[4];
#pragma unroll
    for (int n = 0; n < 4; ++n) acc[n] = (f32x4){0.f, 0.f, 0.f, 0.f};

    for (int kt = 0; kt < LK; kt += 64) {
        __syncthreads();   // protect LDS vs previous tile's reads
        if (tid < 64) {
            const float* kp = kpos + (size_t)(b * LK + kt + tid) * 3;
            const int m = kmask[b * LK + kt + tid];
            float kx = kp[0];
            if (m) kx = 3.0e37f;          // d2 -> inf -> score exactly 0
            s_kx[tid] = kx; s_ky[tid] = kp[1]; s_kz[tid] = kp[2];
        }
        {
            const unsigned short* src = vt_base + (size_t)vv * LK + kt + vc * 8;
            uint4 d0 = *(const uint4*)src;
            uint4 d1 = *(const uint4*)(src + (size_t)32 * LK);
            *(uint4*)&sV[vv * SP + vc * 8]        = d0;
            *(uint4*)&sV[(vv + 32) * SP + vc * 8] = d1;
        }
        __syncthreads();

        // scores: 2 octets of 8 k each
#pragma unroll
        for (int p = 0; p < 2; ++p) {
            const int o = so + 4 * p;
            float kxa[8], kya[8], kza[8];
            *(float4*)&kxa[0] = *(const float4*)&s_kx[o * 8];
            *(float4*)&kxa[4] = *(const float4*)&s_kx[o * 8 + 4];
            *(float4*)&kya[0] = *(const float4*)&s_ky[o * 8];
            *(float4*)&kya[4] = *(const float4*)&s_ky[o * 8 + 4];
            *(float4*)&kza[0] = *(const float4*)&s_kz[o * 8];
            *(float4*)&kza[4] = *(const float4*)&s_kz[o * 8 + 4];
            unsigned pk[4];
            unsigned short us[8];
#pragma unroll
            for (int j = 0; j < 8; ++j) {
                const float dx = qx - kxa[j];
                const float dy = qy - kya[j];
                const float dz = qz - kza[j];
                const float d2 = fmaf(dx, dx, fmaf(dy, dy, dz * dz));
                const float sc = __expf(d2 * negc);
                pden += sc;
                us[j] = f2bf(sc);
            }
#pragma unroll
            for (int j = 0; j < 4; ++j)
                pk[j] = (unsigned)us[2 * j] | ((unsigned)us[2 * j + 1] << 16);
            *(uint4*)&sS[sq * SP + o * 8] = make_uint4(pk[0], pk[1], pk[2], pk[3]);
        }
        __syncthreads();

        // MFMA: wave handles q-strip [wave*16, wave*16+16), all 64 v
        {
            const unsigned short* ap = &sS[(wave * 16 + ln) * SP + kq * 8];
            const bf16x8 a0 = *(const bf16x8*)(ap);
            const bf16x8 a1 = *(const bf16x8*)(ap + 32);
#pragma unroll
            for (int n = 0; n < 4; ++n) {
                const unsigned short* bp = &sV[(n * 16 + ln) * SP + kq * 8];
                const bf16x8 b0 = *(const bf16x8*)(bp);
                const bf16x8 b1 = *(const bf16x8*)(bp + 32);
                acc[n] = __builtin_amdgcn_mfma_f32_16x16x32_bf16(a0, b0, acc[n], 0, 0, 0);
                acc[n] = __builtin_amdgcn_mfma_f32_16x16x32_bf16(a1, b1, acc[n], 0, 0, 0);
            }
        }
    }

    // denominator reduce: tid = sq*4 + so
    s_pd[tid] = pden;
    __syncthreads();
    if (tid < 64) {
        const float d = s_pd[tid * 4] + s_pd[tid * 4 + 1] +
                        s_pd[tid * 4 + 2] + s_pd[tid * 4 + 3];
        s_inv[tid] = 1.0f / (d + 1e-5f);
    }
    __syncthreads();

    // epilogue: normalize, store attended bf16 [b*Lq][H*V]
#pragma unroll
    for (int n = 0; n < 4; ++n) {
#pragma unroll
        for (int r = 0; r < 4; ++r) {
            const int q = wave * 16 + kq * 4 + r;
            const float val = acc[n][r] * s_inv[q];
            attended[(size_t)(b * LQ + q0 + q) * HV + h * VD + n * 16 + ln] = f2bf(val);
        }
    }
}

// ---------------- projection: C[8192][512] = A_bf16[8192][512] @ W[512][512]^T ----------------
__global__ __launch_bounds__(256) void proj2(
    const unsigned short* __restrict__ A,
    const float* __restrict__ W,
    float* __restrict__ C)
{
    __shared__ unsigned short sA[64 * SP];
    __shared__ unsigned short sW[64 * SP];

    const int tid = threadIdx.x;
    const int n0 = blockIdx.x * 64, m0 = blockIdx.y * 64;
    const int wave = tid >> 6, lane = tid & 63;
    const int ln = lane & 15, kq = lane >> 4;

    const int am = tid >> 3, ac = tid & 7;          // A staging
    const int wn = tid >> 2, wk = (tid & 3) * 16;   // W staging

    f32x4 acc[4];
#pragma unroll
    for (int n = 0; n < 4; ++n) acc[n] = (f32x4){0.f, 0.f, 0.f, 0.f};

    for (int k0 = 0; k0 < 512; k0 += 64) {
        __syncthreads();
        {
            const unsigned short* asrc = A + (size_t)(m0 + am) * 512 + k0 + ac * 8;
            uint4 a0 = *(const uint4*)asrc;
            uint4 a1 = *(const uint4*)(asrc + (size_t)32 * 512);
            *(uint4*)&sA[am * SP + ac * 8]        = a0;
            *(uint4*)&sA[(am + 32) * SP + ac * 8] = a1;
        }
        {
            const float* wsrc = W + (size_t)(n0 + wn) * 512 + k0 + wk;
            float4 w0 = *(const float4*)(wsrc);
            float4 w1 = *(const float4*)(wsrc + 4);
            float4 w2 = *(const float4*)(wsrc + 8);
            float4 w3 = *(const float4*)(wsrc + 12);
            const float wf[16] = {w0.x,w0.y,w0.z,w0.w, w1.x,w1.y,w1.z,w1.w,
                                  w2.x,w2.y,w2.z,w2.w, w3.x,w3.y,w3.z,w3.w};
            unsigned pk[8];
#pragma unroll
            for (int j = 0; j < 8; ++j)
                pk[j] = (unsigned)f2bf(wf[2 * j]) | ((unsigned)f2bf(wf[2 * j + 1]) << 16);
            *(uint4*)&sW[wn * SP + wk]     = make_uint4(pk[0], pk[1], pk[2], pk[3]);
            *(uint4*)&sW[wn * SP + wk + 8] = make_uint4(pk[4], pk[5], pk[6], pk[7]);
        }
        __syncthreads();

        const unsigned short* ap = &sA[(wave * 16 + ln) * SP + kq * 8];
        const bf16x8 a0 = *(const bf16x8*)(ap);
        const bf16x8 a1 = *(const bf16x8*)(ap + 32);
#pragma unroll
        for (int n = 0; n < 4; ++n) {
            const unsigned short* bp = &sW[(n * 16 + ln) * SP + kq * 8];
            const bf16x8 b0 = *(const bf16x8*)(bp);
            const bf16x8 b1 = *(const bf16x8*)(bp + 32);
            acc[n] = __builtin_amdgcn_mfma_f32_16x16x32_bf16(a0, b0, acc[n], 0, 0, 0);
            acc[n] = __builtin_amdgcn_mfma_f32_16x16x32_bf16(a1, b1, acc[n], 0, 0, 0);
        }
    }

#pragma unroll
    for (int n = 0; n < 4; ++n) {
#pragma unroll
        for (int r = 0; r < 4; ++r) {
            C[(size_t)(m0 + wave * 16 + kq * 4 + r) * 512 + n0 + n * 16 + ln] = acc[n][r];
        }
    }
}

extern "C" void kernel_launch(void* const* d_in, const int* in_sizes, int n_in,
                              void* d_out, int out_size, void* d_ws, size_t ws_size,
                              hipStream_t stream) {
    const float* qpos  = (const float*)d_in[0];
    const float* kpos  = (const float*)d_in[1];
    const float* vals  = (const float*)d_in[2];
    const int*   kmask = (const int*)  d_in[3];
    const float* ls    = (const float*)d_in[4];
    const float* wout  = (const float*)d_in[5];
    float* out = (float*)d_out;

    unsigned short* vals_t   = (unsigned short*)d_ws;            // 8 MiB
    unsigned short* attended = vals_t + (size_t)4 * 1024 * 1024; // 8 MiB

    cvt_vals<<<dim3(32, HD, BB), 256, 0, stream>>>(vals, vals_t);
    attend2 <<<dim3(32, HD, BB), 256, 0, stream>>>(qpos, kpos, vals_t, kmask, ls, attended);
    proj2   <<<dim3(OUTD / 64, (BB * LQ) / 64), 256, 0, stream>>>(attended, wout, out);
}